// Round 3
// baseline (123.158 us; speedup 1.0000x reference)
//
#include <hip/hip_runtime.h>
#include <hip/hip_fp16.h>
#include <math.h>

#define BATCH 16
#define CHN   16
#define IMH   96
#define IMW   320
#define HW    (IMH*IMW)          /* 30720 */
#define QB    320                /* q's per gn_accum block (== 64*5) */
#define NBLKQ (HW/QB)            /* 96 blocks per (bb) */
#define NSLOT (HW/64)            /* 480 partial slots per output batch */
#define NPART 27                 /* 21 (sym H) + 6 (b) */
#define RSTRIDE (IMW*CHN)

typedef __attribute__((ext_vector_type(8))) _Float16 h8;

// ---------------- kernel 0: transpose+convert tgt_feat (B,C,H,W) fp32 -> (B,H,W,C) fp16 ----------------
__global__ __launch_bounds__(256) void transpose_tgt(const float* __restrict__ in,
                                                     _Float16* __restrict__ out) {
    const int b = blockIdx.y;
    const int p = blockIdx.x * 256 + threadIdx.x;
    const float* ip = in + (size_t)b * CHN * HW + p;
    h8 lo, hi;
#pragma unroll
    for (int k = 0; k < 8; ++k) {
        lo[k] = (_Float16)ip[k * HW];
        hi[k] = (_Float16)ip[(k + 8) * HW];
    }
    _Float16* op = out + ((size_t)b * HW + p) * CHN;
    *(h8*)(op)     = lo;
    *(h8*)(op + 8) = hi;
}

// round-trip normalize/unnormalize exactly as reference
__device__ __forceinline__ void rt_x(float xp, int& xi, float& wx) {
    float g = 2.0f * (xp + 0.5f) / (float)IMW - 1.0f;
    float x = (g + 1.0f) * ((float)IMW * 0.5f) - 0.5f;
    float x0 = floorf(x);
    wx = x - x0; xi = (int)x0;
}
__device__ __forceinline__ void rt_y(float yp, int& yi, float& wy) {
    float g = 2.0f * (yp + 0.5f) / (float)IMH - 1.0f;
    float y = (g + 1.0f) * ((float)IMH * 0.5f) - 0.5f;
    float y0 = floorf(y);
    wy = y - y0; yi = (int)y0;
}

// ---------------- kernel 1: fused 12-px-cross interp (phase 1) + moments/reduce (phase 2) ----------------
__global__ __launch_bounds__(320) void gn_accum(
    const float* __restrict__ p2,        // (B,2,5,1,H,W)
    const float* __restrict__ P2,        // (B,3,HW)
    const float* __restrict__ calibK,    // (B,3,3)
    const float* __restrict__ weight,    // (B,1,H,W)
    const float* __restrict__ src_feat,  // (B,C,H,W)
    const float* __restrict__ src_w,     // (B,1,H,W)
    const float* __restrict__ tgt_w,     // (B,1,H,W)
    const _Float16* __restrict__ tfT,    // (B,H,W,C) fp16
    float* __restrict__ partials)        // (B, NSLOT, NPART)
{
    __shared__ __align__(16) _Float16 fl[5][QB][CHN];   // 50 KB

    const int n  = blockIdx.x;
    const int bb = n & 15;                // XCD pinning: XCD k holds batches {k,k+8}
    const int kb = n >> 4;                // 0..95
    const int t  = threadIdx.x;           // 0..319
    const int q  = kb * QB + t;

    // ================= phase 1: interpolate all 5 planes at this (bb,q) =================
    const float xc = p2[(size_t)bb * 10 * HW + q];
    const float yc = p2[(size_t)bb * 10 * HW + 5 * HW + q];

    int xi0, xi1, xi2, yi0, yi1, yi2;
    float wx0, wx1, wx2, wy0, wy1, wy2;
    rt_x(xc,         xi0, wx0);
    rt_x(xc + 1.0f,  xi1, wx1);
    rt_x(xc - 1.0f,  xi2, wx2);
    rt_y(yc,         yi0, wy0);
    rt_y(yc + 1.0f,  yi1, wy1);
    rt_y(yc - 1.0f,  yi2, wy2);

    const int bx = min(max(xi0 - 1, 0), IMW - 4);
    const int by = min(max(yi0 - 1, 0), IMH - 4);

    const float omx0 = 1.0f - wx0, omy0 = 1.0f - wy0;
    const int relx1 = xi1 - bx;   // nominal 2 (ULP: 1..3)
    const int relx2 = xi2 - bx;   // nominal 0 (ULP: -1..1)
    const int rely1 = yi1 - by;   // nominal 2
    const int rely2 = yi2 - by;   // nominal 0
    float cw1[4], cw2[4], rw1[4], rw2[4];
#pragma unroll
    for (int j = 0; j < 4; ++j) {
        cw1[j] = (j == relx1 ? 1.0f - wx1 : 0.0f) + (j == relx1 + 1 ? wx1 : 0.0f);
        cw2[j] = (j == relx2 ? 1.0f - wx2 : 0.0f) + (j == relx2 + 1 ? wx2 : 0.0f);
        rw1[j] = (j == rely1 ? 1.0f - wy1 : 0.0f) + (j == rely1 + 1 ? wy1 : 0.0f);
        rw2[j] = (j == rely2 ? 1.0f - wy2 : 0.0f) + (j == rely2 + 1 ? wy2 : 0.0f);
    }

    const _Float16* pbase = tfT + ((size_t)(bb * IMH + by) * IMW + bx) * CHN;

#pragma unroll
    for (int pass = 0; pass < 2; ++pass) {
        const _Float16* bp = pbase + pass * 8;
        // 12-pixel cross (rows 0,3: cols 1,2; rows 1,2: cols 0..3)
        h8 p01 = *(const h8*)(bp + 1 * CHN);
        h8 p02 = *(const h8*)(bp + 2 * CHN);
        h8 p10 = *(const h8*)(bp + RSTRIDE);
        h8 p11 = *(const h8*)(bp + RSTRIDE + 1 * CHN);
        h8 p12 = *(const h8*)(bp + RSTRIDE + 2 * CHN);
        h8 p13 = *(const h8*)(bp + RSTRIDE + 3 * CHN);
        h8 p20 = *(const h8*)(bp + 2 * RSTRIDE);
        h8 p21 = *(const h8*)(bp + 2 * RSTRIDE + 1 * CHN);
        h8 p22 = *(const h8*)(bp + 2 * RSTRIDE + 2 * CHN);
        h8 p23 = *(const h8*)(bp + 2 * RSTRIDE + 3 * CHN);
        h8 p31 = *(const h8*)(bp + 3 * RSTRIDE + 1 * CHN);
        h8 p32 = *(const h8*)(bp + 3 * RSTRIDE + 2 * CHN);

        h8 f0h, f1h, f2h, f3h, f4h;
#pragma unroll
        for (int c = 0; c < 8; ++c) {
            float P01 = (float)p01[c], P02 = (float)p02[c];
            float P10 = (float)p10[c], P11 = (float)p11[c], P12 = (float)p12[c], P13 = (float)p13[c];
            float P20 = (float)p20[c], P21 = (float)p21[c], P22 = (float)p22[c], P23 = (float)p23[c];
            float P31 = (float)p31[c], P32 = (float)p32[c];
            // rowmix over rows 1,2 with y-variant 0 (used by planes 0,1,2)
            float rm0 = omy0 * P10 + wy0 * P20;
            float rm1 = omy0 * P11 + wy0 * P21;
            float rm2 = omy0 * P12 + wy0 * P22;
            float rm3 = omy0 * P13 + wy0 * P23;
            // colmix over cols 1,2 with x-variant 0 (used by planes 0,3,4)
            float cm0 = omx0 * P01 + wx0 * P02;
            float cm1 = omx0 * P11 + wx0 * P12;
            float cm2 = omx0 * P21 + wx0 * P22;
            float cm3 = omx0 * P31 + wx0 * P32;
            float f0 = omy0 * cm1 + wy0 * cm2;
            float f1 = cw1[0] * rm0 + cw1[1] * rm1 + cw1[2] * rm2 + cw1[3] * rm3;
            float f2 = cw2[0] * rm0 + cw2[1] * rm1 + cw2[2] * rm2 + cw2[3] * rm3;
            float f3 = rw1[0] * cm0 + rw1[1] * cm1 + rw1[2] * cm2 + rw1[3] * cm3;
            float f4 = rw2[0] * cm0 + rw2[1] * cm1 + rw2[2] * cm2 + rw2[3] * cm3;
            f0h[c] = (_Float16)f0; f1h[c] = (_Float16)f1; f2h[c] = (_Float16)f2;
            f3h[c] = (_Float16)f3; f4h[c] = (_Float16)f4;
        }
        *(h8*)&fl[0][t][pass * 8] = f0h;
        *(h8*)&fl[1][t][pass * 8] = f1h;
        *(h8*)&fl[2][t][pass * 8] = f2h;
        *(h8*)&fl[3][t][pass * 8] = f3h;
        *(h8*)&fl[4][t][pass * 8] = f4h;
    }
    __syncthreads();

    // ================= phase 2: one output point per thread =================
    const int sBig = t >> 6;              // wave id = plane
    const int m    = t & 63;
    const int S    = sBig * 16 + bb;
    const int num  = S * 30720 + kb * QB; // global G base of this (plane, q-range)
    const int b2   = num / 153600;        // output batch (wave-uniform)
    const int rem  = num - b2 * 153600;
    const int p    = rem / 5 + m;         // output pixel (consecutive per lane)
    const int ql   = 5 * m;               // local q of sample group start

    // 5 sample vectors from LDS
    h8 s0l = *(const h8*)&fl[sBig][ql + 0][0], s0h = *(const h8*)&fl[sBig][ql + 0][8];
    h8 s1l = *(const h8*)&fl[sBig][ql + 1][0], s1h = *(const h8*)&fl[sBig][ql + 1][8];
    h8 s2l = *(const h8*)&fl[sBig][ql + 2][0], s2h = *(const h8*)&fl[sBig][ql + 2][8];
    h8 s3l = *(const h8*)&fl[sBig][ql + 3][0], s3h = *(const h8*)&fl[sBig][ql + 3][8];
    h8 s4l = *(const h8*)&fl[sBig][ql + 4][0], s4h = *(const h8*)&fl[sBig][ql + 4][8];

    // tgt_w bilinear at sample-0 location (plane sBig, (bb, kb*QB+ql)), map of batch b2
    float wtw;
    {
        const float xcw = p2[(size_t)bb * 10 * HW + kb * QB + ql];
        const float ycw = p2[(size_t)bb * 10 * HW + 5 * HW + kb * QB + ql];
        float xpw = xcw + (sBig == 1 ? 1.0f : (sBig == 2 ? -1.0f : 0.0f));
        float ypw = ycw + (sBig == 3 ? 1.0f : (sBig == 4 ? -1.0f : 0.0f));
        int xiw, yiw; float wxw, wyw;
        rt_x(xpw, xiw, wxw);
        rt_y(ypw, yiw, wyw);
        xiw = min(max(xiw, 0), IMW - 2);
        yiw = min(max(yiw, 0), IMH - 2);
        const float* twb = tgt_w + (size_t)b2 * HW + yiw * IMW + xiw;
        float v00 = twb[0], v01 = twb[1], v10 = twb[IMW], v11 = twb[IMW + 1];
        wtw = v00 * (1.0f - wxw) * (1.0f - wyw) + v01 * wxw * (1.0f - wyw)
            + v10 * (1.0f - wxw) * wyw          + v11 * wxw * wyw;
    }
    const float wP  = weight[(size_t)b2 * HW + p];
    const float swP = src_w[(size_t)b2 * HW + p];
    const float w   = swP * wtw * wP;

    // pixel Jacobian rows
    const float* P2b = P2 + (size_t)b2 * 3 * HW;
    const float X = P2b[p], Y = P2b[HW + p], Z = P2b[2 * HW + p];
    const float fx = calibK[b2 * 9 + 0];
    const float fy = calibK[b2 * 9 + 4];
    const float fxZ = fx / Z, fyZ = fy / Z;
    const float fxXZ2 = fxZ * X / Z;
    const float fyYZ2 = fyZ * Y / Z;
    float r0[6] = { fxZ, 0.0f, -fxXZ2, -fxXZ2 * Y, fx + fxXZ2 * X, -fxZ * Y };
    float r1[6] = { 0.0f, fyZ, -fyYZ2, -fy - fyYZ2 * Y, fyYZ2 * X, fyZ * X };

    // channel-reduced moments
    float Sxx = 0.0f, Sxy = 0.0f, Syy = 0.0f, Tx = 0.0f, Ty = 0.0f;
    const float* srcb = src_feat + (size_t)b2 * CHN * HW + p;
#pragma unroll
    for (int c = 0; c < 16; ++c) {
        float f0 = (c < 8) ? (float)s0l[c] : (float)s0h[c - 8];
        float f1 = (c < 8) ? (float)s1l[c] : (float)s1h[c - 8];
        float f2 = (c < 8) ? (float)s2l[c] : (float)s2h[c - 8];
        float f3 = (c < 8) ? (float)s3l[c] : (float)s3h[c - 8];
        float f4 = (c < 8) ? (float)s4l[c] : (float)s4h[c - 8];
        float sv  = srcb[c * HW];
        float res = sv - f0;
        float gx  = (f1 - f2) * 0.5f;
        float gy  = (f3 - f4) * 0.5f;
        Sxx += gx * gx; Sxy += gx * gy; Syy += gy * gy;
        Tx  += res * gx; Ty  += res * gy;
    }

    const float Pm = w * Sxx, Qm = w * Sxy, Rm = w * Syy;
    const float tx = w * Tx,  ty = w * Ty;

    // per-wave reduce (each wave has its own (b2, slot)); lane 0 writes 27 floats
    const int r5   = S % 5;
    const int slot = 96 * r5 + kb;
    float* pout = partials + ((size_t)b2 * NSLOT + slot) * NPART;

    int idx = 0;
#pragma unroll
    for (int k = 0; k < 6; ++k) {
#pragma unroll
        for (int l = 0; l < 6; ++l) {
            if (l < k) continue;
            float v = Pm * r0[k] * r0[l]
                    + Qm * (r0[k] * r1[l] + r1[k] * r0[l])
                    + Rm * r1[k] * r1[l];
            v += __shfl_down(v, 32); v += __shfl_down(v, 16);
            v += __shfl_down(v, 8);  v += __shfl_down(v, 4);
            v += __shfl_down(v, 2);  v += __shfl_down(v, 1);
            if (m == 0) pout[idx] = v;
            ++idx;
        }
    }
#pragma unroll
    for (int k = 0; k < 6; ++k) {
        float v = tx * r0[k] + ty * r1[k];
        v += __shfl_down(v, 32); v += __shfl_down(v, 16);
        v += __shfl_down(v, 8);  v += __shfl_down(v, 4);
        v += __shfl_down(v, 2);  v += __shfl_down(v, 1);
        if (m == 0) pout[21 + k] = v;
    }
}

// ---------------- kernel 2: double reduce + solve + se3_exp + compose ----------------
__global__ __launch_bounds__(256) void gn_solve(
    const float* __restrict__ partials,
    const float* __restrict__ poses,
    float* __restrict__ out)
{
    const int b = blockIdx.x;
    const int t = threadIdx.x;
    __shared__ double dsum[8][NPART];
    __shared__ double sums[NPART];

    if (t < 216) {
        const int col = t % NPART;
        const int g   = t / NPART;     // 0..7
        double s = 0.0;
        for (int j = g; j < NSLOT; j += 8)
            s += (double)partials[((size_t)b * NSLOT + j) * NPART + col];
        dsum[g][col] = s;
    }
    __syncthreads();
    if (t < NPART) {
        double s = 0.0;
#pragma unroll
        for (int g = 0; g < 8; ++g) s += dsum[g][t];
        sums[t] = s;
    }
    __syncthreads();
    if (t != 0) return;

    double A[6][7];
    {
        int idx = 0;
        for (int k = 0; k < 6; ++k)
            for (int l = k; l < 6; ++l) {
                A[k][l] = sums[idx];
                A[l][k] = sums[idx];
                ++idx;
            }
        for (int k = 0; k < 6; ++k) A[k][6] = sums[21 + k];
    }
    for (int col = 0; col < 6; ++col) {
        int piv = col; double mx = fabs(A[col][col]);
        for (int rr = col + 1; rr < 6; ++rr) {
            double v = fabs(A[rr][col]);
            if (v > mx) { mx = v; piv = rr; }
        }
        if (piv != col)
            for (int j = col; j < 7; ++j) { double tmp = A[col][j]; A[col][j] = A[piv][j]; A[piv][j] = tmp; }
        double d = A[col][col];
        for (int rr = col + 1; rr < 6; ++rr) {
            double f = A[rr][col] / d;
            for (int j = col; j < 7; ++j) A[rr][j] -= f * A[col][j];
        }
    }
    double x[6];
    for (int i = 5; i >= 0; --i) {
        double s = A[i][6];
        for (int j = i + 1; j < 6; ++j) s -= A[i][j] * x[j];
        x[i] = s / A[i][i];
    }

    const double rho[3] = { x[0], x[1], x[2] };
    const double phi[3] = { x[3], x[4], x[5] };
    const double th2 = phi[0]*phi[0] + phi[1]*phi[1] + phi[2]*phi[2];
    const bool small = th2 < 1e-8;
    const double th2s = small ? 1.0 : th2;
    const double th = sqrt(th2s);
    const double Ac = small ? 1.0 - th2 / 6.0   : sin(th) / th;
    const double Bc = small ? 0.5 - th2 / 24.0  : (1.0 - cos(th)) / th2s;
    const double Cc = small ? 1.0/6.0 - th2/120.0 : (th - sin(th)) / (th2s * th);
    const double Kh[3][3] = { { 0.0, -phi[2],  phi[1] },
                              {  phi[2], 0.0, -phi[0] },
                              { -phi[1],  phi[0], 0.0 } };
    double K2[3][3];
    for (int i = 0; i < 3; ++i)
        for (int j = 0; j < 3; ++j) {
            double s = 0.0;
            for (int k = 0; k < 3; ++k) s += Kh[i][k] * Kh[k][j];
            K2[i][j] = s;
        }
    double T[4][4];
    for (int i = 0; i < 3; ++i)
        for (int j = 0; j < 3; ++j) {
            double I = (i == j) ? 1.0 : 0.0;
            T[i][j] = I + Ac * Kh[i][j] + Bc * K2[i][j];
        }
    for (int i = 0; i < 3; ++i) {
        double s = 0.0;
        for (int j = 0; j < 3; ++j) {
            double I = (i == j) ? 1.0 : 0.0;
            double V = I + Bc * Kh[i][j] + Cc * K2[i][j];
            s += V * rho[j];
        }
        T[i][3] = s;
    }
    T[3][0] = 0.0; T[3][1] = 0.0; T[3][2] = 0.0; T[3][3] = 1.0;

    const float* pz = poses + b * 16;
    for (int i = 0; i < 4; ++i)
        for (int j = 0; j < 4; ++j) {
            double s = 0.0;
            for (int k = 0; k < 4; ++k) s += T[i][k] * (double)pz[k * 4 + j];
            out[b * 16 + i * 4 + j] = (float)s;
        }
    for (int k = 0; k < 6; ++k)
        out[BATCH * 16 + b * 6 + k] = (float)x[k];
}

extern "C" void kernel_launch(void* const* d_in, const int* in_sizes, int n_in,
                              void* d_out, int out_size, void* d_ws, size_t ws_size,
                              hipStream_t stream) {
    const float* poses    = (const float*)d_in[0];
    const float* calibK   = (const float*)d_in[1];
    const float* p2       = (const float*)d_in[2];
    const float* P2       = (const float*)d_in[3];
    const float* weight   = (const float*)d_in[4];
    const float* src_feat = (const float*)d_in[5];
    const float* tgt_feat = (const float*)d_in[6];
    const float* src_w    = (const float*)d_in[7];
    const float* tgt_w    = (const float*)d_in[8];
    float* out = (float*)d_out;

    _Float16* tfT   = (_Float16*)d_ws;                          // B*HW*C halves (15.7 MB)
    float* partials = (float*)(tfT + (size_t)BATCH * HW * CHN); // B*NSLOT*NPART floats (0.83 MB)

    hipLaunchKernelGGL(transpose_tgt, dim3(HW / 256, BATCH), dim3(256), 0, stream,
                       tgt_feat, tfT);
    hipLaunchKernelGGL(gn_accum, dim3(NBLKQ * BATCH), dim3(QB), 0, stream,
                       p2, P2, calibK, weight, src_feat, src_w, tgt_w, tfT, partials);
    hipLaunchKernelGGL(gn_solve, dim3(BATCH), dim3(256), 0, stream,
                       partials, poses, out);
}

// Round 4
// 63.961 us; speedup vs baseline: 1.9255x; 1.9255x over previous
//
#include <hip/hip_runtime.h>
#include <math.h>

#define BATCH 16
#define CHN   16
#define IMH   96
#define IMW   320
#define HW    (IMH*IMW)          /* 30720 */
#define NBLK  (HW/256)           /* 120 blocks per batch */
#define NPART 27                 /* 21 (sym H) + 6 (b) */
#define ROWB  (IMW*16)           /* fp8 row stride in bytes */

typedef __attribute__((ext_vector_type(2))) float f32x2;

__device__ __forceinline__ int comp4(int4 v, int k) {
    switch (k) { case 0: return v.x; case 1: return v.y; case 2: return v.z; default: return v.w; }
}

// ---------------- kernel 0: transpose+quantize tgt_feat (B,C,H,W) fp32 -> (B,H,W,16) fp8 e4m3 ----------------
__global__ __launch_bounds__(256) void transpose_tgt(const float* __restrict__ in,
                                                     char* __restrict__ out) {
    const int b = blockIdx.y;
    const int p = blockIdx.x * 256 + threadIdx.x;
    const float* ip = in + (size_t)b * CHN * HW + p;
    float f[16];
#pragma unroll
    for (int c = 0; c < 16; ++c) f[c] = ip[c * HW];
    int4 pk;
    int* pw = &pk.x;
#pragma unroll
    for (int k = 0; k < 4; ++k) {
        int dw = __builtin_amdgcn_cvt_pk_fp8_f32(f[4 * k + 0], f[4 * k + 1], 0, false);
        dw     = __builtin_amdgcn_cvt_pk_fp8_f32(f[4 * k + 2], f[4 * k + 3], dw, true);
        pw[k] = dw;
    }
    *(int4*)(out + ((size_t)b * HW + p) * 16) = pk;
}

// ---------------- kernel 1: per-point moments + block-partial H/b (fp8 gathers) ----------------
__global__ __launch_bounds__(256, 3) void gn_accum(
    const float* __restrict__ p2,        // (B,2,5,1,H,W)
    const float* __restrict__ P2,        // (B,3,HW)
    const float* __restrict__ calibK,    // (B,3,3)
    const float* __restrict__ weight,    // (B,1,H,W)
    const float* __restrict__ src_feat,  // (B,C,H,W)
    const float* __restrict__ src_w,     // (B,1,H,W)
    const float* __restrict__ tgt_w,     // (B,1,H,W)
    const char* __restrict__ tf8,        // (B,H,W,16) fp8
    float* __restrict__ partials)        // (B, NBLK, NPART)
{
    // XCD pinning: XCD k serves batches {k, k+8} -> 2 fp8 maps (1.6 MB) per L2
    const int n   = blockIdx.x;
    const int b   = n & 15;
    const int blk = n >> 4;
    const int p   = blk * 256 + threadIdx.x;

    // ---- scrambled grid coords (output point (b,p) pulls G=(b*HW+p)*5+s) ----
    int   off[5];          // byte offset of (y0,x0) corner in map b
    float wxs[5], wys[5];
    int   pix00 = 0;
    const unsigned Gbase = ((unsigned)b * HW + (unsigned)p) * 5u;
#pragma unroll
    for (int s = 0; s < 5; ++s) {
        unsigned G    = Gbase + (unsigned)s;
        unsigned sBig = G / (unsigned)(BATCH * HW);
        unsigned r    = G - sBig * (unsigned)(BATCH * HW);
        unsigned bb   = r / (unsigned)HW;
        unsigned q    = r - bb * (unsigned)HW;
        const float* pb = p2 + (size_t)bb * (10 * HW) + (size_t)sBig * HW + q;
        float xp = pb[0];
        float yp = pb[5 * HW];
        float gx = 2.0f * (xp + 0.5f) / (float)IMW - 1.0f;
        float gy = 2.0f * (yp + 0.5f) / (float)IMH - 1.0f;
        float x  = (gx + 1.0f) * ((float)IMW * 0.5f) - 0.5f;
        float y  = (gy + 1.0f) * ((float)IMH * 0.5f) - 0.5f;
        float x0 = floorf(x), y0 = floorf(y);
        wxs[s] = x - x0;
        wys[s] = y - y0;
        int xi = (int)x0, yi = (int)y0;
        xi = min(max(xi, 0), IMW - 2);
        yi = min(max(yi, 0), IMH - 2);
        off[s] = ((b * IMH + yi) * IMW + xi) * 16;
        if (s == 0) pix00 = b * HW + yi * IMW + xi;
    }

    // ---- issue all 20 fp8 corner loads (16B each = full 16 channels) ----
    int4 LA[5], LB[5], LC[5], LD[5];
#pragma unroll
    for (int s = 0; s < 5; ++s) {
        const char* bp = tf8 + off[s];
        LA[s] = *(const int4*)(bp);
        LB[s] = *(const int4*)(bp + 16);
        LC[s] = *(const int4*)(bp + ROWB);
        LD[s] = *(const int4*)(bp + ROWB + 16);
    }

    // ---- pixel Jacobian rows ----
    const float* P2b = P2 + (size_t)b * 3 * HW;
    const float X = P2b[p], Y = P2b[HW + p], Z = P2b[2 * HW + p];
    const float fx = calibK[b * 9 + 0];
    const float fy = calibK[b * 9 + 4];
    const float fxZ = fx / Z, fyZ = fy / Z;
    const float fxXZ2 = fxZ * X / Z;
    const float fyYZ2 = fyZ * Y / Z;
    float r0[6] = { fxZ, 0.0f, -fxXZ2, -fxXZ2 * Y, fx + fxXZ2 * X, -fxZ * Y };
    float r1[6] = { 0.0f, fyZ, -fyYZ2, -fy - fyYZ2 * Y, fyYZ2 * X, fyZ * X };

    // ---- weights ----
    const float wP  = weight[(size_t)b * HW + p];
    const float swP = src_w[(size_t)b * HW + p];
    float wtw;
    {
        float wx = wxs[0], wy = wys[0];
        const float* twb = tgt_w + pix00;
        float v00 = twb[0], v01 = twb[1], v10 = twb[IMW], v11 = twb[IMW + 1];
        wtw = v00 * (1.0f - wx) * (1.0f - wy) + v01 * wx * (1.0f - wy)
            + v10 * (1.0f - wx) * wy          + v11 * wx * wy;
    }
    const float w = swP * wtw * wP;

    // per-sample bilinear corner weights
    float w00[5], w01[5], w10[5], w11[5];
#pragma unroll
    for (int s = 0; s < 5; ++s) {
        float wx = wxs[s], wy = wys[s];
        w00[s] = (1.0f - wx) * (1.0f - wy);
        w01[s] = wx * (1.0f - wy);
        w10[s] = (1.0f - wx) * wy;
        w11[s] = wx * wy;
    }

    // ---- channel-dword passes: decode fp8, bilinear-mix, accumulate moments ----
    float Sxx = 0.0f, Sxy = 0.0f, Syy = 0.0f, Tx = 0.0f, Ty = 0.0f;
    const float* srcb = src_feat + (size_t)b * CHN * HW + p;

#pragma unroll
    for (int k = 0; k < 4; ++k) {
        float fs[5][4];
#pragma unroll
        for (int s = 0; s < 5; ++s) {
            f32x2 alo = __builtin_amdgcn_cvt_pk_f32_fp8(comp4(LA[s], k), false);
            f32x2 ahi = __builtin_amdgcn_cvt_pk_f32_fp8(comp4(LA[s], k), true);
            f32x2 blo = __builtin_amdgcn_cvt_pk_f32_fp8(comp4(LB[s], k), false);
            f32x2 bhi = __builtin_amdgcn_cvt_pk_f32_fp8(comp4(LB[s], k), true);
            f32x2 clo = __builtin_amdgcn_cvt_pk_f32_fp8(comp4(LC[s], k), false);
            f32x2 chi = __builtin_amdgcn_cvt_pk_f32_fp8(comp4(LC[s], k), true);
            f32x2 dlo = __builtin_amdgcn_cvt_pk_f32_fp8(comp4(LD[s], k), false);
            f32x2 dhi = __builtin_amdgcn_cvt_pk_f32_fp8(comp4(LD[s], k), true);
            float a[4] = { alo[0], alo[1], ahi[0], ahi[1] };
            float bq[4] = { blo[0], blo[1], bhi[0], bhi[1] };
            float c[4] = { clo[0], clo[1], chi[0], chi[1] };
            float d[4] = { dlo[0], dlo[1], dhi[0], dhi[1] };
#pragma unroll
            for (int j = 0; j < 4; ++j)
                fs[s][j] = a[j] * w00[s] + bq[j] * w01[s] + c[j] * w10[s] + d[j] * w11[s];
        }
#pragma unroll
        for (int j = 0; j < 4; ++j) {
            float sv  = srcb[(4 * k + j) * HW];
            float res = sv - fs[0][j];
            float gx  = (fs[1][j] - fs[2][j]) * 0.5f;
            float gy  = (fs[3][j] - fs[4][j]) * 0.5f;
            Sxx += gx * gx; Sxy += gx * gy; Syy += gy * gy;
            Tx  += res * gx; Ty  += res * gy;
        }
    }

    const float Pm = w * Sxx, Qm = w * Sxy, Rm = w * Syy;
    const float tx = w * Tx,  ty = w * Ty;

    // ---- 27 per-point values, block tree-reduce ----
    __shared__ float red[4][NPART];
    const int lane = threadIdx.x & 63, wv = threadIdx.x >> 6;

    int idx = 0;
#pragma unroll
    for (int k = 0; k < 6; ++k) {
#pragma unroll
        for (int l = 0; l < 6; ++l) {
            if (l < k) continue;
            float v = Pm * r0[k] * r0[l]
                    + Qm * (r0[k] * r1[l] + r1[k] * r0[l])
                    + Rm * r1[k] * r1[l];
            v += __shfl_down(v, 32); v += __shfl_down(v, 16);
            v += __shfl_down(v, 8);  v += __shfl_down(v, 4);
            v += __shfl_down(v, 2);  v += __shfl_down(v, 1);
            if (lane == 0) red[wv][idx] = v;
            ++idx;
        }
    }
#pragma unroll
    for (int k = 0; k < 6; ++k) {
        float v = tx * r0[k] + ty * r1[k];
        v += __shfl_down(v, 32); v += __shfl_down(v, 16);
        v += __shfl_down(v, 8);  v += __shfl_down(v, 4);
        v += __shfl_down(v, 2);  v += __shfl_down(v, 1);
        if (lane == 0) red[wv][21 + k] = v;
    }
    __syncthreads();
    if (threadIdx.x < NPART) {
        float s = red[0][threadIdx.x] + red[1][threadIdx.x]
                + red[2][threadIdx.x] + red[3][threadIdx.x];
        partials[((size_t)b * NBLK + blk) * NPART + threadIdx.x] = s;
    }
}

// ---------------- kernel 2: double reduce + solve + se3_exp + compose ----------------
__global__ __launch_bounds__(256) void gn_solve(
    const float* __restrict__ partials,
    const float* __restrict__ poses,
    float* __restrict__ out)
{
    const int b = blockIdx.x;
    const int t = threadIdx.x;
    __shared__ double dsum[8][NPART];
    __shared__ double sums[NPART];

    if (t < 216) {
        const int col = t % NPART;
        const int g   = t / NPART;     // 0..7
        double s = 0.0;
        for (int j = g; j < NBLK; j += 8)
            s += (double)partials[((size_t)b * NBLK + j) * NPART + col];
        dsum[g][col] = s;
    }
    __syncthreads();
    if (t < NPART) {
        double s = 0.0;
#pragma unroll
        for (int g = 0; g < 8; ++g) s += dsum[g][t];
        sums[t] = s;
    }
    __syncthreads();
    if (t != 0) return;

    double A[6][7];
    {
        int idx = 0;
        for (int k = 0; k < 6; ++k)
            for (int l = k; l < 6; ++l) {
                A[k][l] = sums[idx];
                A[l][k] = sums[idx];
                ++idx;
            }
        for (int k = 0; k < 6; ++k) A[k][6] = sums[21 + k];
    }
    for (int col = 0; col < 6; ++col) {
        int piv = col; double mx = fabs(A[col][col]);
        for (int rr = col + 1; rr < 6; ++rr) {
            double v = fabs(A[rr][col]);
            if (v > mx) { mx = v; piv = rr; }
        }
        if (piv != col)
            for (int j = col; j < 7; ++j) { double tmp = A[col][j]; A[col][j] = A[piv][j]; A[piv][j] = tmp; }
        double d = A[col][col];
        for (int rr = col + 1; rr < 6; ++rr) {
            double f = A[rr][col] / d;
            for (int j = col; j < 7; ++j) A[rr][j] -= f * A[col][j];
        }
    }
    double x[6];
    for (int i = 5; i >= 0; --i) {
        double s = A[i][6];
        for (int j = i + 1; j < 6; ++j) s -= A[i][j] * x[j];
        x[i] = s / A[i][i];
    }

    const double rho[3] = { x[0], x[1], x[2] };
    const double phi[3] = { x[3], x[4], x[5] };
    const double th2 = phi[0]*phi[0] + phi[1]*phi[1] + phi[2]*phi[2];
    const bool small = th2 < 1e-8;
    const double th2s = small ? 1.0 : th2;
    const double th = sqrt(th2s);
    const double Ac = small ? 1.0 - th2 / 6.0   : sin(th) / th;
    const double Bc = small ? 0.5 - th2 / 24.0  : (1.0 - cos(th)) / th2s;
    const double Cc = small ? 1.0/6.0 - th2/120.0 : (th - sin(th)) / (th2s * th);
    const double Kh[3][3] = { { 0.0, -phi[2],  phi[1] },
                              {  phi[2], 0.0, -phi[0] },
                              { -phi[1],  phi[0], 0.0 } };
    double K2[3][3];
    for (int i = 0; i < 3; ++i)
        for (int j = 0; j < 3; ++j) {
            double s = 0.0;
            for (int k = 0; k < 3; ++k) s += Kh[i][k] * Kh[k][j];
            K2[i][j] = s;
        }
    double T[4][4];
    for (int i = 0; i < 3; ++i)
        for (int j = 0; j < 3; ++j) {
            double I = (i == j) ? 1.0 : 0.0;
            T[i][j] = I + Ac * Kh[i][j] + Bc * K2[i][j];
        }
    for (int i = 0; i < 3; ++i) {
        double s = 0.0;
        for (int j = 0; j < 3; ++j) {
            double I = (i == j) ? 1.0 : 0.0;
            double V = I + Bc * Kh[i][j] + Cc * K2[i][j];
            s += V * rho[j];
        }
        T[i][3] = s;
    }
    T[3][0] = 0.0; T[3][1] = 0.0; T[3][2] = 0.0; T[3][3] = 1.0;

    const float* pz = poses + b * 16;
    for (int i = 0; i < 4; ++i)
        for (int j = 0; j < 4; ++j) {
            double s = 0.0;
            for (int k = 0; k < 4; ++k) s += T[i][k] * (double)pz[k * 4 + j];
            out[b * 16 + i * 4 + j] = (float)s;
        }
    for (int k = 0; k < 6; ++k)
        out[BATCH * 16 + b * 6 + k] = (float)x[k];
}

extern "C" void kernel_launch(void* const* d_in, const int* in_sizes, int n_in,
                              void* d_out, int out_size, void* d_ws, size_t ws_size,
                              hipStream_t stream) {
    const float* poses    = (const float*)d_in[0];
    const float* calibK   = (const float*)d_in[1];
    const float* p2       = (const float*)d_in[2];
    const float* P2       = (const float*)d_in[3];
    const float* weight   = (const float*)d_in[4];
    const float* src_feat = (const float*)d_in[5];
    const float* tgt_feat = (const float*)d_in[6];
    const float* src_w    = (const float*)d_in[7];
    const float* tgt_w    = (const float*)d_in[8];
    float* out = (float*)d_out;

    char*  tf8      = (char*)d_ws;                            // B*HW*16 bytes (7.9 MB)
    float* partials = (float*)(tf8 + (size_t)BATCH * HW * 16); // B*NBLK*NPART floats

    hipLaunchKernelGGL(transpose_tgt, dim3(HW / 256, BATCH), dim3(256), 0, stream,
                       tgt_feat, tf8);
    hipLaunchKernelGGL(gn_accum, dim3(NBLK * BATCH), dim3(256), 0, stream,
                       p2, P2, calibK, weight, src_feat, src_w, tgt_w, tf8, partials);
    hipLaunchKernelGGL(gn_solve, dim3(BATCH), dim3(256), 0, stream,
                       partials, poses, out);
}